// Round 4
// baseline (382.128 us; speedup 1.0000x reference)
//
#include <hip/hip_runtime.h>
#include <hip/hip_bf16.h>
#include <cmath>

// PSNR + 3D-SSIM, pred/gt (N=4, C=16->D, H=512, W=512) f32.
// R4: K1 2px/thread, S/D arrays only (squares recomputed per tap) -> no spill;
//     K2 tile 16x64 (LDS 25.5 KB -> 6 blocks/CU), b128 W-blur window reads,
//     4-row H strips, fewer barriers.

#define NB 4
#define DD 16
#define HH 512
#define WW 512
#define SLICE (HH * WW)   // 2^18
#define VOL (DD * SLICE)
#define C1F 0.0001f
#define C2F 0.0009f

struct GW { float g[11]; };

__device__ inline float blo(unsigned v) {  // low bf16 -> f32 (exact)
  union { unsigned u; float f; } c; c.u = v << 16; return c.f;
}
__device__ inline float bhi(unsigned v) {  // high bf16 -> f32 (exact)
  union { unsigned u; float f; } c; c.u = v & 0xFFFF0000u; return c.f;
}
__device__ inline unsigned pack_bf2(float a, float b) {  // (lo=a, hi=b), RNE
  __hip_bfloat162 t;
  t.x = __float2bfloat16(a);
  t.y = __float2bfloat16(b);
  union { __hip_bfloat162 h; unsigned u; } c; c.h = t; return c.u;
}

__device__ inline float block_sum256(float v) {
#pragma unroll
  for (int o = 32; o > 0; o >>= 1) v += __shfl_down(v, o, 64);
  __shared__ float r[4];
  if ((threadIdx.x & 63) == 0) r[threadIdx.x >> 6] = v;
  __syncthreads();
  float out = 0.f;
  if (threadIdx.x == 0) out = r[0] + r[1] + r[2] + r[3];
  __syncthreads();
  return out;
}

__global__ void zero_acc_k(float* acc) {
  if (threadIdx.x < 8) acc[threadIdx.x] = 0.f;
}

// K1: 2 (h,w) px per thread. Keep only S=p+q, D=p-q in registers (32 floats);
// squares recomputed inside the blur. Write (Sb,Db) -> P1, (S2b,D2b) -> P2
// as bf16x2 u32 per px (uint2 per thread). Fused PSNR partial.
__global__ __launch_bounds__(256, 4) void dblur_k(
    const float* __restrict__ pred, const float* __restrict__ gt,
    unsigned* __restrict__ P1, unsigned* __restrict__ P2,
    float* __restrict__ acc, GW gw) {
  int tid = blockIdx.x * 256 + threadIdx.x;   // 0 .. NB*SLICE/2
  int n = tid >> 17;                          // 131072 px-pairs per n
  int s = (tid & 131071) * 2;
  const float* pb = pred + (size_t)n * VOL + s;
  const float* qb = gt + (size_t)n * VOL + s;
  float S[DD][2], Dm[DD][2];
  float sd = 0.f;
#pragma unroll
  for (int d = 0; d < DD; ++d) {
    float2 p = *(const float2*)(pb + d * SLICE);
    float2 q = *(const float2*)(qb + d * SLICE);
    float s0 = p.x + q.x, s1 = p.y + q.y;
    float d0 = p.x - q.x, d1 = p.y - q.y;
    S[d][0] = s0; S[d][1] = s1;
    Dm[d][0] = d0; Dm[d][1] = d1;
    sd = fmaf(d0, d0, sd); sd = fmaf(d1, d1, sd);
  }
  float bs = block_sum256(sd);
  if (threadIdx.x == 0) atomicAdd(&acc[n], bs);
  size_t base = ((size_t)n * DD) * SLICE + s;
#pragma unroll
  for (int dout = 0; dout < DD; ++dout) {
    float a0[2] = {0.f, 0.f}, a1[2] = {0.f, 0.f};
    float a2[2] = {0.f, 0.f}, a3[2] = {0.f, 0.f};
#pragma unroll
    for (int k = 0; k < 11; ++k) {
      int j = dout + k - 5; j = j < 0 ? 0 : (j > DD - 1 ? DD - 1 : j);
      float w = gw.g[k];
#pragma unroll
      for (int c = 0; c < 2; ++c) {
        float ts = w * S[j][c], td = w * Dm[j][c];
        a0[c] += ts;                       // blur(S)
        a1[c] += td;                       // blur(D)
        a2[c] = fmaf(ts, S[j][c], a2[c]);  // blur(S^2)
        a3[c] = fmaf(td, Dm[j][c], a3[c]); // blur(D^2)
      }
    }
    uint2 v1 = make_uint2(pack_bf2(a0[0], a1[0]), pack_bf2(a0[1], a1[1]));
    uint2 v2 = make_uint2(pack_bf2(a2[0], a3[0]), pack_bf2(a2[1], a3[1]));
    *(uint2*)(P1 + base + dout * SLICE) = v1;
    *(uint2*)(P2 + base + dout * SLICE) = v2;
  }
}

// K2 tile geometry: 16h x 64w outputs, halo 26x74, float2 LDS stride 76.
#define TTH 16
#define TTW 64
#define INH 26
#define INWR 74
#define LSTR 76   // float2 stride; even -> float4 casts stay 16B-aligned

// One pass: stage bf16x2 pair -> float2 LDS, H-blur (4-row strips), W-blur
// (sliding 14-window via 7 b128 reads). out[4] = this thread's 4 outputs at
// (row = tid>>4, x = (tid&15)*4 ..+3).
__device__ inline void pass_blur(const unsigned* __restrict__ P, size_t base,
                                 int th0, int tw0, const GW& gw,
                                 float2* tin2, float2* tmp2, float2 out[4]) {
  int tid = threadIdx.x;
  for (int i = tid; i < INH * INWR; i += 256) {
    int y = i / INWR, x = i - y * INWR;
    int gy = th0 + y - 5; gy = gy < 0 ? 0 : (gy > HH - 1 ? HH - 1 : gy);
    int gx = tw0 + x - 5; gx = gx < 0 ? 0 : (gx > WW - 1 ? WW - 1 : gx);
    unsigned v = P[base + gy * WW + gx];
    tin2[y * LSTR + x] = make_float2(blo(v), bhi(v));
  }
  __syncthreads();
  // H-blur: item = (4-row strip, col); 14 b64 reads -> 4 float2 outputs
  for (int i = tid; i < 4 * INWR; i += 256) {   // 296 items
    int strip = i / INWR, c = i - strip * INWR;
    int r0 = strip * 4;
    float2 w[14];
#pragma unroll
    for (int k = 0; k < 14; ++k) w[k] = tin2[(r0 + k) * LSTR + c];
#pragma unroll
    for (int j = 0; j < 4; ++j) {
      float ax = 0.f, ay = 0.f;
#pragma unroll
      for (int k = 0; k < 11; ++k) {
        ax = fmaf(gw.g[k], w[j + k].x, ax);
        ay = fmaf(gw.g[k], w[j + k].y, ay);
      }
      tmp2[(r0 + j) * LSTR + c] = make_float2(ax, ay);
    }
  }
  __syncthreads();
  // W-blur: thread owns (row = tid>>4, 4 x at xs=(tid&15)*4); window of 14
  // float2 read as 7 float4 (aligned: LSTR even, xs % 4 == 0).
  int row = tid >> 4, xs = (tid & 15) * 4;
  const float4* t4 = (const float4*)(tmp2 + row * LSTR + xs);
  float2 w[14];
#pragma unroll
  for (int k = 0; k < 7; ++k) {
    float4 v = t4[k];
    w[2 * k] = make_float2(v.x, v.y);
    w[2 * k + 1] = make_float2(v.z, v.w);
  }
#pragma unroll
  for (int j = 0; j < 4; ++j) {
    float ax = 0.f, ay = 0.f;
#pragma unroll
    for (int k = 0; k < 11; ++k) {
      ax = fmaf(gw.g[k], w[j + k].x, ax);
      ay = fmaf(gw.g[k], w[j + k].y, ay);
    }
    out[j] = make_float2(ax, ay);
  }
}

__global__ __launch_bounds__(256) void hw_ssim_k(
    const unsigned* __restrict__ P1, const unsigned* __restrict__ P2,
    float* __restrict__ acc, GW gw) {
  __shared__ __align__(16) float2 tin2[INH * LSTR];
  __shared__ __align__(16) float2 tmp2[TTH * LSTR];
  int b = blockIdx.x;
  int tile = b & 255;           // 32 h-tiles x 8 w-tiles
  int d = (b >> 8) & 15;
  int n = b >> 12;
  int th0 = (tile >> 3) * TTH;
  int tw0 = (tile & 7) * TTW;
  size_t base = (size_t)(n * DD + d) << 18;
  float2 r0[4], r1[4];
  pass_blur(P1, base, th0, tw0, gw, tin2, tmp2, r0);  // (Sb, Db)
  pass_blur(P2, base, th0, tw0, gw, tin2, tmp2, r1);  // (S2b, D2b)
  float ssum = 0.f;
#pragma unroll
  for (int j = 0; j < 4; ++j) {
    float Sb = r0[j].x, Db = r0[j].y, B1 = r1[j].x, B2 = r1[j].y;
    float SS = Sb * Sb, DDm = Db * Db;
    float m12_2 = (SS - DDm) * 0.5f;     // 2*mu1*mu2
    float msq   = (SS + DDm) * 0.5f;     // mu1^2 + mu2^2
    float Epq   = (B1 - B2) * 0.25f;     // E[pq]
    float Esum  = (B1 + B2) * 0.5f;      // E[p^2+q^2]
    float sig12_2 = 2.f * Epq - m12_2;   // 2*sigma12
    float svar    = Esum - msq;          // sigma1^2 + sigma2^2
    float num = (m12_2 + C1F) * (sig12_2 + C2F);
    float den = (msq + C1F) * (svar + C2F);
    ssum += num / den;
  }
  float bs = block_sum256(ssum);
  if (threadIdx.x == 0) atomicAdd(&acc[4 + n], bs);
}

__global__ void final_k(const float* __restrict__ acc, float* __restrict__ out) {
  if (threadIdx.x == 0 && blockIdx.x == 0) {
    double psnr = 0.0, ssim = 0.0;
    for (int n = 0; n < NB; ++n) {
      double mse = (double)acc[n] / (double)VOL;
      psnr += 10.0 * log10(1.0 / mse);
      ssim += (double)acc[4 + n] / (double)VOL;
    }
    out[0] = (float)psnr;
    out[1] = (float)ssim;
    out[2] = (float)NB;
  }
}

extern "C" void kernel_launch(void* const* d_in, const int* in_sizes, int n_in,
                              void* d_out, int out_size, void* d_ws, size_t ws_size,
                              hipStream_t stream) {
  const float* pred = (const float*)d_in[0];
  const float* gt = (const float*)d_in[1];
  unsigned* P1 = (unsigned*)d_ws;                       // NB*VOL u32 = 67 MB
  unsigned* P2 = P1 + (size_t)NB * VOL;                 // NB*VOL u32 = 67 MB
  float* acc = (float*)(P2 + (size_t)NB * VOL);
  GW gw;
  double t[11], s = 0.0;
  for (int i = 0; i < 11; ++i) {
    double x = i - 5;
    t[i] = exp(-(x * x) / 4.5);
    s += t[i];
  }
  for (int i = 0; i < 11; ++i) gw.g[i] = (float)(t[i] / s);

  zero_acc_k<<<1, 64, 0, stream>>>(acc);
  dblur_k<<<NB * SLICE / 512, 256, 0, stream>>>(pred, gt, P1, P2, acc, gw);
  hw_ssim_k<<<NB * DD * 256, 256, 0, stream>>>(P1, P2, acc, gw);
  final_k<<<1, 1, 0, stream>>>(acc, (float*)d_out);
}

// Round 5
// 278.021 us; speedup vs baseline: 1.3745x; 1.3745x over previous
//
#include <hip/hip_runtime.h>
#include <hip/hip_bf16.h>
#include <cmath>

// PSNR + 3D-SSIM, pred/gt (N=4, C=16->D, H=512, W=512) f32.
// R5: single interleaved field array F[nd*SLICE+s] = uint2(pk(S,D), pk(S2,D2)).
//     K1: 2px/thread, one uint4 store per dout (single write stream).
//     K2: phase A = global->register H-blur (column windows, L1-cached halo),
//         bf16-packed H-blurred tile -> LDS (19.5 KB); phase B = b128 window
//         reads (stride 76, <=2-way in-phase = free), W-blur + SSIM in regs.
//     LDS traffic ~6x down, 3 barriers/block.

#define NB 4
#define DD 16
#define HH 512
#define WW 512
#define SLICE (HH * WW)   // 2^18
#define VOL (DD * SLICE)
#define C1F 0.0001f
#define C2F 0.0009f

struct GW { float g[11]; };

__device__ inline float blo(unsigned v) {  // low bf16 -> f32 (exact)
  union { unsigned u; float f; } c; c.u = v << 16; return c.f;
}
__device__ inline float bhi(unsigned v) {  // high bf16 -> f32 (exact)
  union { unsigned u; float f; } c; c.u = v & 0xFFFF0000u; return c.f;
}
__device__ inline unsigned pack_bf2(float a, float b) {  // (lo=a, hi=b), RNE
  __hip_bfloat162 t;
  t.x = __float2bfloat16(a);
  t.y = __float2bfloat16(b);
  union { __hip_bfloat162 h; unsigned u; } c; c.h = t; return c.u;
}

__device__ inline float block_sum256(float v) {
#pragma unroll
  for (int o = 32; o > 0; o >>= 1) v += __shfl_down(v, o, 64);
  __shared__ float r[4];
  if ((threadIdx.x & 63) == 0) r[threadIdx.x >> 6] = v;
  __syncthreads();
  float out = 0.f;
  if (threadIdx.x == 0) out = r[0] + r[1] + r[2] + r[3];
  __syncthreads();
  return out;
}

__global__ void zero_acc_k(float* acc) {
  if (threadIdx.x < 8) acc[threadIdx.x] = 0.f;
}

// K1: 2 px/thread; D-blur of {S,D,S2,D2}; one uint4 store per dout into the
// interleaved F array. Fused PSNR partial.
__global__ __launch_bounds__(256, 4) void dblur_k(
    const float* __restrict__ pred, const float* __restrict__ gt,
    uint2* __restrict__ F, float* __restrict__ acc, GW gw) {
  int tid = blockIdx.x * 256 + threadIdx.x;   // 0 .. NB*SLICE/2
  int n = tid >> 17;
  int s = (tid & 131071) * 2;
  const float* pb = pred + (size_t)n * VOL + s;
  const float* qb = gt + (size_t)n * VOL + s;
  float S[DD][2], Dm[DD][2];
  float sd = 0.f;
#pragma unroll
  for (int d = 0; d < DD; ++d) {
    float2 p = *(const float2*)(pb + d * SLICE);
    float2 q = *(const float2*)(qb + d * SLICE);
    float s0 = p.x + q.x, s1 = p.y + q.y;
    float d0 = p.x - q.x, d1 = p.y - q.y;
    S[d][0] = s0; S[d][1] = s1;
    Dm[d][0] = d0; Dm[d][1] = d1;
    sd = fmaf(d0, d0, sd); sd = fmaf(d1, d1, sd);
  }
  float bs = block_sum256(sd);
  if (threadIdx.x == 0) atomicAdd(&acc[n], bs);
#pragma unroll
  for (int dout = 0; dout < DD; ++dout) {
    float a0[2] = {0.f, 0.f}, a1[2] = {0.f, 0.f};
    float a2[2] = {0.f, 0.f}, a3[2] = {0.f, 0.f};
#pragma unroll
    for (int k = 0; k < 11; ++k) {
      int j = dout + k - 5; j = j < 0 ? 0 : (j > DD - 1 ? DD - 1 : j);
      float w = gw.g[k];
#pragma unroll
      for (int c = 0; c < 2; ++c) {
        float ts = w * S[j][c], td = w * Dm[j][c];
        a0[c] += ts;
        a1[c] += td;
        a2[c] = fmaf(ts, S[j][c], a2[c]);
        a3[c] = fmaf(td, Dm[j][c], a3[c]);
      }
    }
    uint4 v;
    v.x = pack_bf2(a0[0], a1[0]);  // px0 (Sb, Db)
    v.y = pack_bf2(a2[0], a3[0]);  // px0 (S2b, D2b)
    v.z = pack_bf2(a0[1], a1[1]);  // px1
    v.w = pack_bf2(a2[1], a3[1]);
    *(uint4*)(F + (size_t)(n * DD + dout) * SLICE + s) = v;
  }
}

// K2 geometry: 32h x 64w output tile; A-halo cols 74; tmp uint2 stride 76.
#define TH 32
#define TW 64
#define ACOLS 74
#define AITEMS (4 * ACOLS)   // 296 column-strip items (4 strips of 8 rows)
#define ST2 76

__global__ __launch_bounds__(256, 4) void hw_ssim_k(
    const uint2* __restrict__ F, float* __restrict__ acc, GW gw) {
  __shared__ uint2 tmp[TH * ST2];   // 19.5 KB, H-blurred bf16x4 tile
  int b = blockIdx.x;
  int tile = b & 127;
  int nd = b >> 7;                  // n*16 + d
  int n = nd >> 4;
  int th0 = (tile >> 3) * TH;
  int tw0 = (tile & 7) * TW;
  const uint2* base = F + (size_t)nd * SLICE;
  int tid = threadIdx.x;
  // ---- phase A: global column windows -> register H-blur -> LDS tile ----
  for (int i = tid; i < AITEMS; i += 256) {
    int strip = i / ACOLS;          // 0..3  (8 output rows each)
    int c = i - strip * ACOLS;      // 0..73
    int gx = tw0 + c - 5; gx = gx < 0 ? 0 : (gx > WW - 1 ? WW - 1 : gx);
    int r0 = th0 + strip * 8;
    uint2 w[18];
#pragma unroll
    for (int t = 0; t < 18; ++t) {
      int gy = r0 + t - 5; gy = gy < 0 ? 0 : (gy > HH - 1 ? HH - 1 : gy);
      w[t] = base[gy * WW + gx];
    }
    float a0[8], a1[8], a2[8], a3[8];
#pragma unroll
    for (int j = 0; j < 8; ++j) { a0[j] = a1[j] = a2[j] = a3[j] = 0.f; }
#pragma unroll
    for (int t = 0; t < 18; ++t) {
      float Sv = blo(w[t].x), Dv = bhi(w[t].x);
      float S2v = blo(w[t].y), D2v = bhi(w[t].y);
#pragma unroll
      for (int j = 0; j < 8; ++j) {
        if (t - j >= 0 && t - j <= 10) {      // compile-time folded
          float g = gw.g[t - j];
          a0[j] = fmaf(g, Sv, a0[j]);
          a1[j] = fmaf(g, Dv, a1[j]);
          a2[j] = fmaf(g, S2v, a2[j]);
          a3[j] = fmaf(g, D2v, a3[j]);
        }
      }
    }
    int lr0 = strip * 8;
#pragma unroll
    for (int j = 0; j < 8; ++j)
      tmp[(lr0 + j) * ST2 + c] =
          make_uint2(pack_bf2(a0[j], a1[j]), pack_bf2(a2[j], a3[j]));
  }
  __syncthreads();
  // ---- phase B: b128 window reads, W-blur + SSIM in registers ----
  int row = tid >> 3, m = tid & 7, x0 = m * 8;
  const uint4* wp = (const uint4*)(tmp + row * ST2 + x0);  // 16B-aligned
  uint4 W4[9];
#pragma unroll
  for (int k = 0; k < 9; ++k) W4[k] = wp[k];
  float b0[8], b1[8], b2[8], b3[8];
#pragma unroll
  for (int j = 0; j < 8; ++j) { b0[j] = b1[j] = b2[j] = b3[j] = 0.f; }
#pragma unroll
  for (int t = 0; t < 18; ++t) {
    unsigned pu = (t & 1) ? W4[t >> 1].z : W4[t >> 1].x;
    unsigned qu = (t & 1) ? W4[t >> 1].w : W4[t >> 1].y;
    float Sv = blo(pu), Dv = bhi(pu), S2v = blo(qu), D2v = bhi(qu);
#pragma unroll
    for (int j = 0; j < 8; ++j) {
      if (t - j >= 0 && t - j <= 10) {
        float g = gw.g[t - j];
        b0[j] = fmaf(g, Sv, b0[j]);
        b1[j] = fmaf(g, Dv, b1[j]);
        b2[j] = fmaf(g, S2v, b2[j]);
        b3[j] = fmaf(g, D2v, b3[j]);
      }
    }
  }
  float ssum = 0.f;
#pragma unroll
  for (int j = 0; j < 8; ++j) {
    float Sb = b0[j], Db = b1[j], B1 = b2[j], B2 = b3[j];
    float SS = Sb * Sb, DDm = Db * Db;
    float m12_2 = (SS - DDm) * 0.5f;     // 2*mu1*mu2
    float msq   = (SS + DDm) * 0.5f;     // mu1^2 + mu2^2
    float Epq   = (B1 - B2) * 0.25f;     // E[pq]
    float Esum  = (B1 + B2) * 0.5f;      // E[p^2+q^2]
    float sig12_2 = 2.f * Epq - m12_2;   // 2*sigma12
    float svar    = Esum - msq;          // sigma1^2 + sigma2^2
    float num = (m12_2 + C1F) * (sig12_2 + C2F);
    float den = (msq + C1F) * (svar + C2F);
    ssum += num / den;
  }
  float bsum = block_sum256(ssum);
  if (threadIdx.x == 0) atomicAdd(&acc[4 + n], bsum);
}

__global__ void final_k(const float* __restrict__ acc, float* __restrict__ out) {
  if (threadIdx.x == 0 && blockIdx.x == 0) {
    double psnr = 0.0, ssim = 0.0;
    for (int n = 0; n < NB; ++n) {
      double mse = (double)acc[n] / (double)VOL;
      psnr += 10.0 * log10(1.0 / mse);
      ssim += (double)acc[4 + n] / (double)VOL;
    }
    out[0] = (float)psnr;
    out[1] = (float)ssim;
    out[2] = (float)NB;
  }
}

extern "C" void kernel_launch(void* const* d_in, const int* in_sizes, int n_in,
                              void* d_out, int out_size, void* d_ws, size_t ws_size,
                              hipStream_t stream) {
  const float* pred = (const float*)d_in[0];
  const float* gt = (const float*)d_in[1];
  uint2* F = (uint2*)d_ws;                          // NB*VOL uint2 = 134 MB
  float* acc = (float*)(F + (size_t)NB * VOL);
  GW gw;
  double t[11], s = 0.0;
  for (int i = 0; i < 11; ++i) {
    double x = i - 5;
    t[i] = exp(-(x * x) / 4.5);
    s += t[i];
  }
  for (int i = 0; i < 11; ++i) gw.g[i] = (float)(t[i] / s);

  zero_acc_k<<<1, 64, 0, stream>>>(acc);
  dblur_k<<<NB * SLICE / 512, 256, 0, stream>>>(pred, gt, F, acc, gw);
  hw_ssim_k<<<NB * DD * 128, 256, 0, stream>>>(F, acc, gw);
  final_k<<<1, 1, 0, stream>>>(acc, (float*)d_out);
}